// Round 9
// baseline (4448.599 us; speedup 1.0000x reference)
//
#include <hip/hip_runtime.h>
#include <hip/hip_bf16.h>

// PointNetMSG on MI355X. Inputs FP32, output FP32. Internal fp32, ws bf16.
// B=4, N=16384, Cs=32, M=1024, scales: (r=0.1,k=32),(r=0.2,k=64).
// R9: FPS protocol v4 — RELAXED-AGENT load polling (no RMW serialization),
// owner pushes winner features through a parity-double-buffered LLC mailbox
// (atomicExch + return-dependency ordering, zero fences).

static constexpr int Bb = 4;
static constexpr int Npts = 16384;
static constexpr int Mc = 1024;
static constexpr int NBLK = 16;                      // fps blocks per batch
static constexpr int OUT_EXPECT = 12288 + 1048576;   // new_xyz + feats
#define BN_EPS 1e-5f
#define SLOPE 0.02f
#define SCOPE_AGT __HIP_MEMORY_SCOPE_AGENT

// ---- workspace layout (total 1,687,552 B; ws_size >= this proven R4) ----
static constexpr size_t OFF_STATS = 33024;    // f32 [2][384]
static constexpr size_t OFF_NORM  = 36864;    // f32 [2][384]
static constexpr size_t OFF_MBOX  = 40960;    // u64 [4][16][2][16] = 16 KB feats mailbox
static constexpr size_t ZERO_BYTES = 65536;
static constexpr size_t OFF_CIDX  = 65536;    // i32 [4][1024]
static constexpr size_t OFF_IDX0  = 81920;    // u16 [4][1024][32]
static constexpr size_t OFF_CNT0  = 344064;   // i32 [4][1024]
static constexpr size_t OFF_IDX1  = 360448;   // u16 [4][1024][64]
static constexpr size_t OFF_CNT1  = 884736;   // i32 [4][1024]
static constexpr size_t OFF_ATTN  = 901120;   // bf16 [4][32][1024]
static constexpr size_t OFF_Z0    = 1163264;  // bf16 [4][64][1024]
static constexpr size_t WS_REQUIRED = 1687552;
// fps val slots u64[4][1024][16] = 524288 B, aliased over attn+z0 (fps-only lifetime)
static constexpr size_t OFF_FSLOT = 901120;
static constexpr size_t FSLOT_BYTES = (size_t)Bb * Mc * NBLK * 8;

__device__ __forceinline__ float sup_at(const float* xyz, const float* pf,
                                        int b, int c, int n) {
  return (c < 3) ? xyz[((size_t)b*3 + c)*Npts + n]
                 : pf[((size_t)b*29 + (c-3))*Npts + n];
}

__device__ __forceinline__ float sanf(float v, float repl) {
  if (!(v == v) || fabsf(v) > 1e30f) v = repl;
  return v;
}

__global__ __launch_bounds__(256) void fill_kernel(float* out, int n, float val) {
  int i = blockIdx.x * 256 + threadIdx.x;
  if (i < n) out[i] = val;
}

// ---- K1: FPS v4. 16 blocks x 512 threads per batch, 2 pts/thread in VGPRs.
// Distance arithmetic bit-identical to R6-R8 (sequential __fadd_rn chain).
__global__ __launch_bounds__(512, 2) void fps_kernel(
    const float* __restrict__ xyz, const float* __restrict__ pf,
    int* __restrict__ cidx, unsigned long long* __restrict__ slots,
    unsigned long long* __restrict__ mbox) {
  const int blk = blockIdx.x;
  const int b = blk >> 4;
  const int sb = blk & (NBLK - 1);
  const int tid = threadIdx.x;
  const int lane = tid & 63, wid = tid >> 6;
  float f0[32], f1[32];
  const int p0 = sb * 1024 + tid;
  const int p1 = p0 + 512;
  float d0 = 1e10f, d1 = 1e10f;
#pragma unroll
  for (int c = 0; c < 32; ++c) {
    f0[c] = sup_at(xyz, pf, b, c, p0);
    f1[c] = sup_at(xyz, pf, b, c, p1);
  }
  __shared__ float cf[32];
  __shared__ unsigned long long red[8];
  if (sb == 0 && tid == 0) cidx[b * Mc] = 0;
  if (tid < 32) cf[tid] = sup_at(xyz, pf, b, tid, 0);   // centroid 0 = point 0
  __syncthreads();
  unsigned long long* slotb = slots + (size_t)b * Mc * NBLK;
  unsigned long long* mboxb = mbox + (size_t)b * NBLK * 2 * 16;
  for (int it = 0; it < Mc - 1; ++it) {
    const int par = it & 1;
    // ---- local distance update (exact R6 arithmetic) ----
    float cc[32];
#pragma unroll
    for (int c = 0; c < 32; ++c) cc[c] = cf[c];
    {
      float d = 0.f, e = 0.f;
#pragma unroll
      for (int c = 0; c < 32; ++c) {
        float t0 = f0[c] - cc[c];
        float s0 = __fmul_rn(t0, t0);
        d = (c == 0) ? s0 : __fadd_rn(d, s0);
        float t1 = f1[c] - cc[c];
        float s1 = __fmul_rn(t1, t1);
        e = (c == 0) ? s1 : __fadd_rn(e, s1);
      }
      d0 = fminf(d0, d);
      d1 = fminf(d1, e);
    }
    float bd; int bp;
    if (d0 >= d1) { bd = d0; bp = p0; } else { bd = d1; bp = p1; }  // p0<p1: first-index tiebreak
    unsigned long long v =
        ((unsigned long long)__float_as_uint(bd) << 32) | (unsigned int)(~(unsigned int)bp);
#pragma unroll
    for (int d = 32; d; d >>= 1) {
      unsigned long long o = __shfl_xor(v, d, 64);
      if (o > v) v = o;
    }
    if (lane == 0) red[wid] = v;
    __syncthreads();
    // ---- block best (all threads; identifies the owner thread) ----
    unsigned long long vb = red[0];
#pragma unroll
    for (int w = 1; w < 8; ++w) if (red[w] > vb) vb = red[w];
    const int bpb = (int)(~(unsigned int)(vb & 0xffffffffu)) & (Npts - 1);
    const int plocal = bpb - sb * 1024;        // [0,2048)
    // ---- owner: push features to mailbox (LLC RMW), then publish val ----
    if (tid == (plocal & 511)) {
      unsigned long long* mb = mboxb + ((size_t)sb * 2 + par) * 16;
      unsigned long long oldOr = 0;
      if ((plocal >> 9) == 0) {
#pragma unroll
        for (int c = 0; c < 16; ++c) {
          unsigned long long pk = ((unsigned long long)__float_as_uint(f0[2*c+1]) << 32)
                                  | __float_as_uint(f0[2*c]);
          oldOr |= atomicExch(&mb[c], pk);
        }
      } else {
#pragma unroll
        for (int c = 0; c < 16; ++c) {
          unsigned long long pk = ((unsigned long long)__float_as_uint(f1[2*c+1]) << 32)
                                  | __float_as_uint(f1[2*c]);
          oldOr |= atomicExch(&mb[c], pk);
        }
      }
      // dependency barrier: forces vmcnt wait on all exch returns before the
      // val publish issues. Branch body is benign if it ever fires.
      if (oldOr == 0xDEADBEEFCAFEBABEull)
        atomicAdd((unsigned int*)&slotb[(size_t)it * NBLK + sb], 0u);
      atomicMax(&slotb[(size_t)it * NBLK + sb], vb);   // val != 0 always (~idx != 0)
    }
    // ---- wave 0: poll 16 val slots (LLC-direct loads), read winner mailbox ----
    if (wid == 0) {
      unsigned long long myv = 0;
      if (lane < NBLK) {
        const unsigned long long* sp = &slotb[(size_t)it * NBLK + lane];
        while ((myv = __hip_atomic_load(sp, __ATOMIC_RELAXED, SCOPE_AGT)) == 0ull)
          __builtin_amdgcn_s_sleep(1);
      }
      unsigned long long mv = myv;
#pragma unroll
      for (int d = 8; d; d >>= 1) {
        unsigned long long o = __shfl_xor(mv, d, 16);
        if (o > mv) mv = o;
      }
      unsigned long long vwin = __shfl(mv, 0, 64);
      unsigned long long mask = __ballot(lane < NBLK && myv == vwin);
      int sbWin = (int)__builtin_ctzll(mask);
      if (lane < 16) {
        unsigned long long w = __hip_atomic_load(
            &mboxb[((size_t)sbWin * 2 + par) * 16 + lane], __ATOMIC_RELAXED, SCOPE_AGT);
        cf[2*lane]     = __uint_as_float((unsigned int)(w & 0xffffffffu));
        cf[2*lane + 1] = __uint_as_float((unsigned int)(w >> 32));
      }
      if (lane == 0 && sb == 0) {
        int idxWin = (int)(~(unsigned int)(vwin & 0xffffffffu)) & (Npts - 1);
        cidx[b * Mc + it + 1] = idxWin;
      }
    }
    __syncthreads();
  }
}

// ---- K2 (runs last): new_xyz output, f32 ----
__global__ __launch_bounds__(256) void gather_kernel(
    const float* __restrict__ xyz, const int* __restrict__ cidx,
    float* __restrict__ oxyz, int out_size) {
  int idx = blockIdx.x * 256 + threadIdx.x;   // B*3*M = 12288
  if (idx >= out_size || idx >= 12288) return;
  int m = idx & (Mc - 1);
  int t = idx >> 10;          // b*3 + c
  int b = t / 3;
  int ci = cidx[b * Mc + m] & (Npts - 1);
  oxyz[idx] = sanf(xyz[(size_t)t * Npts + ci], 888.0f);
}

// ---- K3: ball grouping, both radii in one pass; u16 index lists ----
__global__ __launch_bounds__(256) void ball_kernel(
    const float* __restrict__ xyz, const float* __restrict__ pf,
    const int* __restrict__ cidx,
    unsigned short* __restrict__ idx0, int* __restrict__ cnt0,
    unsigned short* __restrict__ idx1, int* __restrict__ cnt1) {
  const int b = blockIdx.x >> 6;
  const int mt = blockIdx.x & 63;
  const int tid = threadIdx.x;
  __shared__ float cf[16][32];
  __shared__ float csq[16];
  __shared__ unsigned int ent[16][128];
  __shared__ int lcnt[16];
  for (int i = tid; i < 16 * 32; i += 256) {
    int ml = i >> 5, c = i & 31;
    int ci = cidx[b * Mc + mt * 16 + ml] & (Npts - 1);
    cf[ml][c] = sup_at(xyz, pf, b, c, ci);
  }
  if (tid < 16) lcnt[tid] = 0;
  __syncthreads();
  if (tid < 16) {
    float a = 0.f;
#pragma unroll
    for (int c = 0; c < 32; ++c) a = fmaf(cf[tid][c], cf[tid][c], a);
    csq[tid] = a;
  }
  __syncthreads();
  for (int ch = 0; ch < Npts / 256; ++ch) {
    int p = ch * 256 + tid;
    float x[32];
#pragma unroll
    for (int c = 0; c < 32; ++c) x[c] = sup_at(xyz, pf, b, c, p);
    float sp = 0.f;
#pragma unroll
    for (int c = 0; c < 32; ++c) sp = fmaf(x[c], x[c], sp);
#pragma unroll 4
    for (int ml = 0; ml < 16; ++ml) {
      float dot = 0.f;
#pragma unroll
      for (int c = 0; c < 32; ++c) dot = fmaf(cf[ml][c], x[c], dot);
      float d = sp - 2.0f * dot + csq[ml];
      if (d <= 0.04f) {
        int pos = atomicAdd(&lcnt[ml], 1);
        if (pos < 128) ent[ml][pos] = (unsigned int)p | (d <= 0.01f ? 0x80000000u : 0u);
      }
    }
  }
  __syncthreads();
  if (tid < 16) {
    int ml = tid;
    int nn = lcnt[ml]; if (nn > 128) nn = 128;
    for (int i = 1; i < nn; ++i) {   // insertion sort by point index ascending
      unsigned int e = ent[ml][i]; unsigned int key = e & 0x7fffffffu;
      int j = i - 1;
      while (j >= 0 && (ent[ml][j] & 0x7fffffffu) > key) { ent[ml][j+1] = ent[ml][j]; --j; }
      ent[ml][j+1] = e;
    }
    int gm = b * Mc + mt * 16 + ml;
    int c1 = nn < 64 ? nn : 64;
    unsigned short first1 = nn > 0 ? (unsigned short)(ent[ml][0] & 0x7fffffffu) : 0;
    unsigned short* o1 = idx1 + (size_t)gm * 64;
    for (int j = 0; j < 64; ++j)
      o1[j] = j < c1 ? (unsigned short)(ent[ml][j] & 0x7fffffffu) : first1;
    cnt1[gm] = c1;
    unsigned short* o0 = idx0 + (size_t)gm * 32;
    int c0 = 0; unsigned short first0 = 0;
    for (int i = 0; i < nn && c0 < 32; ++i) {
      if (ent[ml][i] & 0x80000000u) {
        unsigned short nv = (unsigned short)(ent[ml][i] & 0x7fffffffu);
        if (c0 == 0) first0 = nv;
        o0[c0++] = nv;
      }
    }
    for (int j = c0; j < 32; ++j) o0[j] = first0;
    cnt0[gm] = c0;
  }
}

// ---- K4: attention, one wave per centroid. o = Wv @ (sum_j softmax_j * y_j). ----
template <int K>
__global__ __launch_bounds__(256) void attn_kernel(
    const float* __restrict__ xyz, const float* __restrict__ pf,
    const int* __restrict__ cidx,
    const unsigned short* __restrict__ idxS, const int* __restrict__ cntS,
    const float* __restrict__ wq, const float* __restrict__ wk,
    const float* __restrict__ wv, const float* __restrict__ wo,
    __hip_bfloat16* __restrict__ outA) {
  __shared__ float WqL[64*33], WkL[64*33], WvL[64*33], WoL[32*65];  // +1 pad rows
  __shared__ float xv[4][32];
  __shared__ float qv[4][64];
  __shared__ float yb[4][2][32];
  __shared__ float ov[4][64];
  __shared__ int cns[4];
  const int tid = threadIdx.x;
  const int wid = tid >> 6, lane = tid & 63;
  const int gid = blockIdx.x;
  const int b = gid >> 8;
  const int m = ((gid & 255) << 2) + wid;
  for (int i = tid; i < 2048; i += 256) {
    int r = i >> 5, c = i & 31;
    WqL[r*33 + c] = wq[i];
    WkL[r*33 + c] = wk[i];
    WvL[r*33 + c] = wv[i];
    int ro = i >> 6, co = i & 63;
    WoL[ro*65 + co] = wo[i];
  }
  if (lane < 32) {
    int ci = cidx[b * Mc + m] & (Npts - 1);
    xv[wid][lane] = sup_at(xyz, pf, b, lane, ci);
  }
  if (lane == 0) cns[wid] = cntS[b * Mc + m];
  __syncthreads();
  {
    float acc = 0.f;
#pragma unroll
    for (int c = 0; c < 32; ++c) acc = fmaf(WqL[lane*33 + c], xv[wid][c], acc);
    qv[wid][lane] = acc;
  }
  __syncthreads();
  int cnt = cns[wid];
  cnt = cnt < 1 ? 1 : (cnt > K ? K : cnt);
  const int jj = lane < K ? lane : 0;
  int nj = (int)idxS[((size_t)b*Mc + m)*K + jj] & (Npts - 1);
  float y[32];
#pragma unroll
  for (int c = 0; c < 32; ++c)
    y[c] = sup_at(xyz, pf, b, c, nj) - xv[wid][c];
  float w0 = 0.f, w1 = 0.f;
#pragma unroll 2
  for (int r = 0; r < 32; ++r) {
    float k0 = 0.f, k1 = 0.f;
#pragma unroll
    for (int c = 0; c < 32; ++c) {
      k0 = fmaf(WkL[r*33 + c], y[c], k0);
      k1 = fmaf(WkL[(r+32)*33 + c], y[c], k1);
    }
    w0 = fmaf(qv[wid][r], k0, w0);
    w1 = fmaf(qv[wid][r+32], k1, w1);
  }
  const float iscale = 0.17677669529663689f;  // 1/sqrt(32)
  w0 *= iscale; w1 *= iscale;
  if (lane >= cnt) { w0 = -1e9f; w1 = -1e9f; }
  float mx0 = w0, mx1 = w1;
#pragma unroll
  for (int d = K/2; d; d >>= 1) {
    mx0 = fmaxf(mx0, __shfl_xor(mx0, d, K));
    mx1 = fmaxf(mx1, __shfl_xor(mx1, d, K));
  }
  float e0 = __expf(w0 - mx0), e1 = __expf(w1 - mx1);
  float s0 = e0, s1 = e1;
#pragma unroll
  for (int d = K/2; d; d >>= 1) {
    s0 += __shfl_xor(s0, d, K);
    s1 += __shfl_xor(s1, d, K);
  }
  float wn0 = e0 / s0, wn1 = e1 / s1;
#pragma unroll
  for (int c = 0; c < 32; ++c) {
    float t0 = wn0 * y[c], t1 = wn1 * y[c];
#pragma unroll
    for (int d = K/2; d; d >>= 1) {
      t0 += __shfl_xor(t0, d, K);
      t1 += __shfl_xor(t1, d, K);
    }
    if (lane == 0) { yb[wid][0][c] = t0; yb[wid][1][c] = t1; }
  }
  __syncthreads();
  {
    const int h = lane >> 5;
    float a2 = 0.f;
#pragma unroll
    for (int c = 0; c < 32; ++c) a2 = fmaf(WvL[lane*33 + c], yb[wid][h][c], a2);
    ov[wid][lane] = a2;
  }
  __syncthreads();
  if (lane < 32) {
    float a3 = 0.f;
#pragma unroll
    for (int r = 0; r < 64; ++r) a3 = fmaf(WoL[lane*65 + r], ov[wid][r], a3);
    outA[((size_t)b*32 + lane)*Mc + m] = __float2bfloat16(a3 + xv[wid][lane]);
  }
}

// ---- K5: conv0 (64x32) + bias, BN stats via atomics ----
__global__ __launch_bounds__(256) void conv0_kernel(
    const __hip_bfloat16* __restrict__ inA, const float* __restrict__ w0,
    const float* __restrict__ b0, __hip_bfloat16* __restrict__ z0,
    float* __restrict__ ssum, float* __restrict__ ssq) {
  int idx = blockIdx.x * 256 + threadIdx.x;   // B*64*M
  int m = idx & (Mc - 1);
  int r = (idx >> 10) & 63;
  int b = idx >> 16;
  float acc = b0[r];
#pragma unroll
  for (int c = 0; c < 32; ++c)
    acc = fmaf(w0[r*32 + c], __bfloat162float(inA[((size_t)b*32 + c)*Mc + m]), acc);
  z0[((size_t)b*64 + r)*Mc + m] = __float2bfloat16(acc);
  float s = acc, q = acc * acc;
#pragma unroll
  for (int d = 32; d; d >>= 1) { s += __shfl_down(s, d, 64); q += __shfl_down(q, d, 64); }
  if ((threadIdx.x & 63) == 0) { atomicAdd(&ssum[r], s); atomicAdd(&ssq[r], q); }
}

// ---- BN finalize ----
__global__ void bnfin_kernel(const float* __restrict__ ssum, const float* __restrict__ ssq,
    const float* __restrict__ g, const float* __restrict__ beta,
    float* __restrict__ A, float* __restrict__ Bn, int nch, float invn) {
  int r = threadIdx.x;
  if (r < nch) {
    float mu = ssum[r] * invn;
    float var = ssq[r] * invn - mu * mu;
    if (var < 0.f) var = 0.f;
    float a = g[r] * rsqrtf(var + BN_EPS);
    A[r] = a;
    Bn[r] = beta[r] - mu * a;
  }
}

// ---- K7: norm0+leaky fused conv1 (128x64). WRITE=false: stats. true: f32 out. ----
template <bool WRITE>
__global__ __launch_bounds__(256) void conv1_kernel(
    const __hip_bfloat16* __restrict__ z0, const float* __restrict__ A0, const float* __restrict__ B0n,
    const float* __restrict__ w1, const float* __restrict__ b1,
    float* __restrict__ ssum, float* __restrict__ ssq,
    const float* __restrict__ A1, const float* __restrict__ B1n,
    float* __restrict__ outAll, int chOff, int out_size) {
  int idx = blockIdx.x * 256 + threadIdx.x;   // B*128*M
  int m = idx & (Mc - 1);
  int r2 = (idx >> 10) & 127;
  int b = idx >> 17;
  float acc = b1[r2];
#pragma unroll 8
  for (int r = 0; r < 64; ++r) {
    float u = fmaf(__bfloat162float(z0[((size_t)b*64 + r)*Mc + m]), A0[r], B0n[r]);
    u = u > 0.f ? u : SLOPE * u;
    acc = fmaf(w1[r2*64 + r], u, acc);
  }
  if (WRITE) {
    float v = fmaf(acc, A1[r2], B1n[r2]);
    size_t oidx = 12288 + ((size_t)b*256 + chOff + r2)*Mc + m;
    if (oidx < (size_t)out_size) outAll[oidx] = sanf(v, 777.0f);
  } else {
    float s = acc, q = acc * acc;
#pragma unroll
    for (int d = 32; d; d >>= 1) { s += __shfl_down(s, d, 64); q += __shfl_down(q, d, 64); }
    if ((threadIdx.x & 63) == 0) { atomicAdd(&ssum[r2], s); atomicAdd(&ssq[r2], q); }
  }
}

extern "C" void kernel_launch(void* const* d_in, const int* in_sizes, int n_in,
                              void* d_out, int out_size, void* d_ws, size_t ws_size,
                              hipStream_t stream) {
  float* outb = (float*)d_out;
  int fillBlocks = (out_size + 255) / 256;
  if (n_in != 26 || in_sizes[0] != Bb*3*Npts || in_sizes[1] != Bb*29*Npts
      || in_sizes[2] != 2048) {
    fill_kernel<<<fillBlocks, 256, 0, stream>>>(outb, out_size, 7777.0f);
    return;
  }
  if (out_size != OUT_EXPECT) {
    fill_kernel<<<fillBlocks, 256, 0, stream>>>(outb, out_size, 23456.0f);
    return;
  }
  if (ws_size < WS_REQUIRED) {
    fill_kernel<<<fillBlocks, 256, 0, stream>>>(outb, out_size, 12345.0f);
    return;
  }
  const float* xyz = (const float*)d_in[0];
  const float* pf  = (const float*)d_in[1];
  char* ws = (char*)d_ws;
  int* cidx = (int*)(ws + OFF_CIDX);
  unsigned short* idx0 = (unsigned short*)(ws + OFF_IDX0);
  int* cnt0 = (int*)(ws + OFF_CNT0);
  unsigned short* idx1 = (unsigned short*)(ws + OFF_IDX1);
  int* cnt1 = (int*)(ws + OFF_CNT1);
  unsigned long long* fslots = (unsigned long long*)(ws + OFF_FSLOT);
  unsigned long long* mboxp = (unsigned long long*)(ws + OFF_MBOX);
  __hip_bfloat16* attn = (__hip_bfloat16*)(ws + OFF_ATTN);
  __hip_bfloat16* z0 = (__hip_bfloat16*)(ws + OFF_Z0);

  hipMemsetAsync(ws, 0, ZERO_BYTES, stream);                 // stats + mailbox etc
  hipMemsetAsync(ws + OFF_FSLOT, 0, FSLOT_BYTES, stream);    // fps val slots
  fps_kernel<<<Bb*NBLK, 512, 0, stream>>>(xyz, pf, cidx, fslots, mboxp);
  ball_kernel<<<Bb*64, 256, 0, stream>>>(xyz, pf, cidx, idx0, cnt0, idx1, cnt1);

  for (int s = 0; s < 2; ++s) {
    const float* aq = (const float*)d_in[2 + s*12 + 0];
    const float* ak = (const float*)d_in[2 + s*12 + 1];
    const float* av = (const float*)d_in[2 + s*12 + 2];
    const float* ao = (const float*)d_in[2 + s*12 + 3];
    const float* w0 = (const float*)d_in[2 + s*12 + 4];
    const float* b0 = (const float*)d_in[2 + s*12 + 5];
    const float* g0 = (const float*)d_in[2 + s*12 + 6];
    const float* t0 = (const float*)d_in[2 + s*12 + 7];
    const float* w1 = (const float*)d_in[2 + s*12 + 8];
    const float* b1 = (const float*)d_in[2 + s*12 + 9];
    const float* g1 = (const float*)d_in[2 + s*12 + 10];
    const float* t1 = (const float*)d_in[2 + s*12 + 11];
    float* st = (float*)(ws + OFF_STATS) + (size_t)s*384;
    float* nrm = (float*)(ws + OFF_NORM) + (size_t)s*384;
    float *sum0 = st, *sq0 = st + 64, *sum1 = st + 128, *sq1 = st + 256;
    float *A0 = nrm, *B0n = nrm + 64, *A1 = nrm + 128, *B1n = nrm + 256;
    if (s == 0)
      attn_kernel<32><<<Bb*Mc/4, 256, 0, stream>>>(xyz, pf, cidx, idx0, cnt0, aq, ak, av, ao, attn);
    else
      attn_kernel<64><<<Bb*Mc/4, 256, 0, stream>>>(xyz, pf, cidx, idx1, cnt1, aq, ak, av, ao, attn);
    conv0_kernel<<<Bb*64*Mc/256, 256, 0, stream>>>(attn, w0, b0, z0, sum0, sq0);
    bnfin_kernel<<<1, 64, 0, stream>>>(sum0, sq0, g0, t0, A0, B0n, 64, 1.0f/4096.0f);
    conv1_kernel<false><<<Bb*128*Mc/256, 256, 0, stream>>>(z0, A0, B0n, w1, b1, sum1, sq1,
                                                           nullptr, nullptr, nullptr, 0, out_size);
    bnfin_kernel<<<1, 128, 0, stream>>>(sum1, sq1, g1, t1, A1, B1n, 128, 1.0f/4096.0f);
    conv1_kernel<true><<<Bb*128*Mc/256, 256, 0, stream>>>(z0, A0, B0n, w1, b1, nullptr, nullptr,
                                                          A1, B1n, outb, s*128, out_size);
  }
  gather_kernel<<<48, 256, 0, stream>>>(xyz, cidx, outb, out_size);
}

// Round 10
// 3653.541 us; speedup vs baseline: 1.2176x; 1.2176x over previous
//
#include <hip/hip_runtime.h>
#include <hip/hip_bf16.h>

// PointNetMSG on MI355X. Inputs FP32, output FP32. Internal fp32, ws bf16.
// B=4, N=16384, Cs=32, M=1024, scales: (r=0.1,k=32),(r=0.2,k=64).
// R10: FPS = R8 protocol (atomicMax publish / atomicAdd(p,0) poll / plain-load
// gather) + NBLK 16->8 (one-line poll set) + per-wave slot ownership with
// candidate-feature prefetch into LDS overlapping the straggler wait.

static constexpr int Bb = 4;
static constexpr int Npts = 16384;
static constexpr int Mc = 1024;
static constexpr int NBLK = 8;                       // fps blocks per batch
static constexpr int OUT_EXPECT = 12288 + 1048576;   // new_xyz + feats
#define BN_EPS 1e-5f
#define SLOPE 0.02f

// ---- workspace layout (total 1,687,552 B; ws_size >= this proven R4) ----
static constexpr size_t OFF_STATS = 33024;    // f32 [2][384]
static constexpr size_t OFF_NORM  = 36864;    // f32 [2][384]
static constexpr size_t ZERO_BYTES = 65536;
static constexpr size_t OFF_CIDX  = 65536;    // i32 [4][1024]
static constexpr size_t OFF_IDX0  = 81920;    // u16 [4][1024][32]
static constexpr size_t OFF_CNT0  = 344064;   // i32 [4][1024]
static constexpr size_t OFF_IDX1  = 360448;   // u16 [4][1024][64]
static constexpr size_t OFF_CNT1  = 884736;   // i32 [4][1024]
static constexpr size_t OFF_ATTN  = 901120;   // bf16 [4][32][1024]
static constexpr size_t OFF_Z0    = 1163264;  // bf16 [4][64][1024]
static constexpr size_t WS_REQUIRED = 1687552;
// fps val slots u64[4][1024][8] = 262144 B, aliased over attn/z0 (fps-only lifetime)
static constexpr size_t OFF_FSLOT = 901120;
static constexpr size_t FSLOT_BYTES = (size_t)Bb * Mc * NBLK * 8;

__device__ __forceinline__ float sup_at(const float* xyz, const float* pf,
                                        int b, int c, int n) {
  return (c < 3) ? xyz[((size_t)b*3 + c)*Npts + n]
                 : pf[((size_t)b*29 + (c-3))*Npts + n];
}

__device__ __forceinline__ float sanf(float v, float repl) {
  if (!(v == v) || fabsf(v) > 1e30f) v = repl;
  return v;
}

__global__ __launch_bounds__(256) void fill_kernel(float* out, int n, float val) {
  int i = blockIdx.x * 256 + threadIdx.x;
  if (i < n) out[i] = val;
}

// ---- K1: FPS v5. 8 blocks x 512 threads per batch, 4 pts/thread in VGPRs.
// Distance arithmetic bit-identical to R6-R9 (sequential __fadd_rn chain).
__global__ __launch_bounds__(512, 1) void fps_kernel(
    const float* __restrict__ xyz, const float* __restrict__ pf,
    int* __restrict__ cidx, unsigned long long* __restrict__ slots) {
  const int blk = blockIdx.x;
  const int b = blk >> 3;
  const int sb = blk & (NBLK - 1);
  const int tid = threadIdx.x;
  const int lane = tid & 63, wid = tid >> 6;
  float f[4][32];
  float dist[4];
  int pidx[4];
#pragma unroll
  for (int i = 0; i < 4; ++i) {
    int p = sb * 2048 + i * 512 + tid;
    pidx[i] = p;
    dist[i] = 1e10f;
#pragma unroll
    for (int c = 0; c < 32; ++c) f[i][c] = sup_at(xyz, pf, b, c, p);
  }
  __shared__ float cf[32];                 // current centroid features
  __shared__ float cand[NBLK][32];         // prefetched candidate features
  __shared__ unsigned long long red[8];
  __shared__ unsigned long long cval[NBLK];
  if (sb == 0 && tid == 0) cidx[b * Mc] = 0;
  if (tid < 32) cf[tid] = sup_at(xyz, pf, b, tid, 0);   // centroid 0 = point 0
  __syncthreads();
  unsigned long long* slotb = slots + (size_t)b * Mc * NBLK;
  for (int it = 0; it < Mc - 1; ++it) {
    // ---- local distance update (exact R6 arithmetic) ----
    float cc[32];
#pragma unroll
    for (int c = 0; c < 32; ++c) cc[c] = cf[c];
    float bestd = -1.0f; int bestp = 0;
#pragma unroll
    for (int i = 0; i < 4; ++i) {
      float d = 0.0f;
#pragma unroll
      for (int c = 0; c < 32; ++c) {
        float t = f[i][c] - cc[c];
        float s = __fmul_rn(t, t);
        d = (c == 0) ? s : __fadd_rn(d, s);
      }
      float nd = fminf(dist[i], d);
      dist[i] = nd;
      if (nd > bestd) { bestd = nd; bestp = pidx[i]; }  // ascending i => first-index tiebreak
    }
    unsigned long long v =
        ((unsigned long long)__float_as_uint(bestd) << 32) | (unsigned int)(~(unsigned int)bestp);
#pragma unroll
    for (int d = 32; d; d >>= 1) {
      unsigned long long o = __shfl_xor(v, d, 64);
      if (o > v) v = o;
    }
    if (lane == 0) red[wid] = v;
    __syncthreads();
    if (tid == 0) {
      unsigned long long vb = red[0];
#pragma unroll
      for (int w = 1; w < 8; ++w) if (red[w] > vb) vb = red[w];
      atomicMax(&slotb[(size_t)it * NBLK + sb], vb);   // publish; val != 0 always
    }
    // ---- wave w: poll slot w (lane0 RMW-spin), prefetch its candidate feats ----
    unsigned long long vw = 0;
    if (lane == 0) {
      unsigned long long* sp = &slotb[(size_t)it * NBLK + wid];
      while ((vw = atomicAdd(sp, 0ull)) == 0ull) { }
    }
    vw = __shfl(vw, 0, 64);
    int pw = (int)(~(unsigned int)(vw & 0xffffffffu)) & (Npts - 1);
    if (lane < 32) cand[wid][lane] = sup_at(xyz, pf, b, lane, pw);
    if (lane == 0) cval[wid] = vw;
    __syncthreads();
    // ---- all threads: select winner among the 8 LDS-resident candidates ----
    unsigned long long vwin = cval[0]; int wblk = 0;
#pragma unroll
    for (int w = 1; w < NBLK; ++w)
      if (cval[w] > vwin) { vwin = cval[w]; wblk = w; }
    if (tid < 32) cf[tid] = cand[wblk][tid];
    if (sb == 0 && tid == 0)
      cidx[b * Mc + it + 1] = (int)(~(unsigned int)(vwin & 0xffffffffu)) & (Npts - 1);
    __syncthreads();
  }
}

// ---- K2 (runs last): new_xyz output, f32 ----
__global__ __launch_bounds__(256) void gather_kernel(
    const float* __restrict__ xyz, const int* __restrict__ cidx,
    float* __restrict__ oxyz, int out_size) {
  int idx = blockIdx.x * 256 + threadIdx.x;   // B*3*M = 12288
  if (idx >= out_size || idx >= 12288) return;
  int m = idx & (Mc - 1);
  int t = idx >> 10;          // b*3 + c
  int b = t / 3;
  int ci = cidx[b * Mc + m] & (Npts - 1);
  oxyz[idx] = sanf(xyz[(size_t)t * Npts + ci], 888.0f);
}

// ---- K3: ball grouping, both radii in one pass; u16 index lists ----
__global__ __launch_bounds__(256) void ball_kernel(
    const float* __restrict__ xyz, const float* __restrict__ pf,
    const int* __restrict__ cidx,
    unsigned short* __restrict__ idx0, int* __restrict__ cnt0,
    unsigned short* __restrict__ idx1, int* __restrict__ cnt1) {
  const int b = blockIdx.x >> 6;
  const int mt = blockIdx.x & 63;
  const int tid = threadIdx.x;
  __shared__ float cf[16][32];
  __shared__ float csq[16];
  __shared__ unsigned int ent[16][128];
  __shared__ int lcnt[16];
  for (int i = tid; i < 16 * 32; i += 256) {
    int ml = i >> 5, c = i & 31;
    int ci = cidx[b * Mc + mt * 16 + ml] & (Npts - 1);
    cf[ml][c] = sup_at(xyz, pf, b, c, ci);
  }
  if (tid < 16) lcnt[tid] = 0;
  __syncthreads();
  if (tid < 16) {
    float a = 0.f;
#pragma unroll
    for (int c = 0; c < 32; ++c) a = fmaf(cf[tid][c], cf[tid][c], a);
    csq[tid] = a;
  }
  __syncthreads();
  for (int ch = 0; ch < Npts / 256; ++ch) {
    int p = ch * 256 + tid;
    float x[32];
#pragma unroll
    for (int c = 0; c < 32; ++c) x[c] = sup_at(xyz, pf, b, c, p);
    float sp = 0.f;
#pragma unroll
    for (int c = 0; c < 32; ++c) sp = fmaf(x[c], x[c], sp);
#pragma unroll 4
    for (int ml = 0; ml < 16; ++ml) {
      float dot = 0.f;
#pragma unroll
      for (int c = 0; c < 32; ++c) dot = fmaf(cf[ml][c], x[c], dot);
      float d = sp - 2.0f * dot + csq[ml];
      if (d <= 0.04f) {
        int pos = atomicAdd(&lcnt[ml], 1);
        if (pos < 128) ent[ml][pos] = (unsigned int)p | (d <= 0.01f ? 0x80000000u : 0u);
      }
    }
  }
  __syncthreads();
  if (tid < 16) {
    int ml = tid;
    int nn = lcnt[ml]; if (nn > 128) nn = 128;
    for (int i = 1; i < nn; ++i) {   // insertion sort by point index ascending
      unsigned int e = ent[ml][i]; unsigned int key = e & 0x7fffffffu;
      int j = i - 1;
      while (j >= 0 && (ent[ml][j] & 0x7fffffffu) > key) { ent[ml][j+1] = ent[ml][j]; --j; }
      ent[ml][j+1] = e;
    }
    int gm = b * Mc + mt * 16 + ml;
    int c1 = nn < 64 ? nn : 64;
    unsigned short first1 = nn > 0 ? (unsigned short)(ent[ml][0] & 0x7fffffffu) : 0;
    unsigned short* o1 = idx1 + (size_t)gm * 64;
    for (int j = 0; j < 64; ++j)
      o1[j] = j < c1 ? (unsigned short)(ent[ml][j] & 0x7fffffffu) : first1;
    cnt1[gm] = c1;
    unsigned short* o0 = idx0 + (size_t)gm * 32;
    int c0 = 0; unsigned short first0 = 0;
    for (int i = 0; i < nn && c0 < 32; ++i) {
      if (ent[ml][i] & 0x80000000u) {
        unsigned short nv = (unsigned short)(ent[ml][i] & 0x7fffffffu);
        if (c0 == 0) first0 = nv;
        o0[c0++] = nv;
      }
    }
    for (int j = c0; j < 32; ++j) o0[j] = first0;
    cnt0[gm] = c0;
  }
}

// ---- K4: attention, one wave per centroid. o = Wv @ (sum_j softmax_j * y_j). ----
template <int K>
__global__ __launch_bounds__(256) void attn_kernel(
    const float* __restrict__ xyz, const float* __restrict__ pf,
    const int* __restrict__ cidx,
    const unsigned short* __restrict__ idxS, const int* __restrict__ cntS,
    const float* __restrict__ wq, const float* __restrict__ wk,
    const float* __restrict__ wv, const float* __restrict__ wo,
    __hip_bfloat16* __restrict__ outA) {
  __shared__ float WqL[64*33], WkL[64*33], WvL[64*33], WoL[32*65];  // +1 pad rows
  __shared__ float xv[4][32];
  __shared__ float qv[4][64];
  __shared__ float yb[4][2][32];
  __shared__ float ov[4][64];
  __shared__ int cns[4];
  const int tid = threadIdx.x;
  const int wid = tid >> 6, lane = tid & 63;
  const int gid = blockIdx.x;
  const int b = gid >> 8;
  const int m = ((gid & 255) << 2) + wid;
  for (int i = tid; i < 2048; i += 256) {
    int r = i >> 5, c = i & 31;
    WqL[r*33 + c] = wq[i];
    WkL[r*33 + c] = wk[i];
    WvL[r*33 + c] = wv[i];
    int ro = i >> 6, co = i & 63;
    WoL[ro*65 + co] = wo[i];
  }
  if (lane < 32) {
    int ci = cidx[b * Mc + m] & (Npts - 1);
    xv[wid][lane] = sup_at(xyz, pf, b, lane, ci);
  }
  if (lane == 0) cns[wid] = cntS[b * Mc + m];
  __syncthreads();
  {
    float acc = 0.f;
#pragma unroll
    for (int c = 0; c < 32; ++c) acc = fmaf(WqL[lane*33 + c], xv[wid][c], acc);
    qv[wid][lane] = acc;
  }
  __syncthreads();
  int cnt = cns[wid];
  cnt = cnt < 1 ? 1 : (cnt > K ? K : cnt);
  const int jj = lane < K ? lane : 0;
  int nj = (int)idxS[((size_t)b*Mc + m)*K + jj] & (Npts - 1);
  float y[32];
#pragma unroll
  for (int c = 0; c < 32; ++c)
    y[c] = sup_at(xyz, pf, b, c, nj) - xv[wid][c];
  float w0 = 0.f, w1 = 0.f;
#pragma unroll 2
  for (int r = 0; r < 32; ++r) {
    float k0 = 0.f, k1 = 0.f;
#pragma unroll
    for (int c = 0; c < 32; ++c) {
      k0 = fmaf(WkL[r*33 + c], y[c], k0);
      k1 = fmaf(WkL[(r+32)*33 + c], y[c], k1);
    }
    w0 = fmaf(qv[wid][r], k0, w0);
    w1 = fmaf(qv[wid][r+32], k1, w1);
  }
  const float iscale = 0.17677669529663689f;  // 1/sqrt(32)
  w0 *= iscale; w1 *= iscale;
  if (lane >= cnt) { w0 = -1e9f; w1 = -1e9f; }
  float mx0 = w0, mx1 = w1;
#pragma unroll
  for (int d = K/2; d; d >>= 1) {
    mx0 = fmaxf(mx0, __shfl_xor(mx0, d, K));
    mx1 = fmaxf(mx1, __shfl_xor(mx1, d, K));
  }
  float e0 = __expf(w0 - mx0), e1 = __expf(w1 - mx1);
  float s0 = e0, s1 = e1;
#pragma unroll
  for (int d = K/2; d; d >>= 1) {
    s0 += __shfl_xor(s0, d, K);
    s1 += __shfl_xor(s1, d, K);
  }
  float wn0 = e0 / s0, wn1 = e1 / s1;
#pragma unroll
  for (int c = 0; c < 32; ++c) {
    float t0 = wn0 * y[c], t1 = wn1 * y[c];
#pragma unroll
    for (int d = K/2; d; d >>= 1) {
      t0 += __shfl_xor(t0, d, K);
      t1 += __shfl_xor(t1, d, K);
    }
    if (lane == 0) { yb[wid][0][c] = t0; yb[wid][1][c] = t1; }
  }
  __syncthreads();
  {
    const int h = lane >> 5;
    float a2 = 0.f;
#pragma unroll
    for (int c = 0; c < 32; ++c) a2 = fmaf(WvL[lane*33 + c], yb[wid][h][c], a2);
    ov[wid][lane] = a2;
  }
  __syncthreads();
  if (lane < 32) {
    float a3 = 0.f;
#pragma unroll
    for (int r = 0; r < 64; ++r) a3 = fmaf(WoL[lane*65 + r], ov[wid][r], a3);
    outA[((size_t)b*32 + lane)*Mc + m] = __float2bfloat16(a3 + xv[wid][lane]);
  }
}

// ---- K5: conv0 (64x32) + bias, BN stats via atomics ----
__global__ __launch_bounds__(256) void conv0_kernel(
    const __hip_bfloat16* __restrict__ inA, const float* __restrict__ w0,
    const float* __restrict__ b0, __hip_bfloat16* __restrict__ z0,
    float* __restrict__ ssum, float* __restrict__ ssq) {
  int idx = blockIdx.x * 256 + threadIdx.x;   // B*64*M
  int m = idx & (Mc - 1);
  int r = (idx >> 10) & 63;
  int b = idx >> 16;
  float acc = b0[r];
#pragma unroll
  for (int c = 0; c < 32; ++c)
    acc = fmaf(w0[r*32 + c], __bfloat162float(inA[((size_t)b*32 + c)*Mc + m]), acc);
  z0[((size_t)b*64 + r)*Mc + m] = __float2bfloat16(acc);
  float s = acc, q = acc * acc;
#pragma unroll
  for (int d = 32; d; d >>= 1) { s += __shfl_down(s, d, 64); q += __shfl_down(q, d, 64); }
  if ((threadIdx.x & 63) == 0) { atomicAdd(&ssum[r], s); atomicAdd(&ssq[r], q); }
}

// ---- BN finalize ----
__global__ void bnfin_kernel(const float* __restrict__ ssum, const float* __restrict__ ssq,
    const float* __restrict__ g, const float* __restrict__ beta,
    float* __restrict__ A, float* __restrict__ Bn, int nch, float invn) {
  int r = threadIdx.x;
  if (r < nch) {
    float mu = ssum[r] * invn;
    float var = ssq[r] * invn - mu * mu;
    if (var < 0.f) var = 0.f;
    float a = g[r] * rsqrtf(var + BN_EPS);
    A[r] = a;
    Bn[r] = beta[r] - mu * a;
  }
}

// ---- K7: norm0+leaky fused conv1 (128x64). WRITE=false: stats. true: f32 out. ----
template <bool WRITE>
__global__ __launch_bounds__(256) void conv1_kernel(
    const __hip_bfloat16* __restrict__ z0, const float* __restrict__ A0, const float* __restrict__ B0n,
    const float* __restrict__ w1, const float* __restrict__ b1,
    float* __restrict__ ssum, float* __restrict__ ssq,
    const float* __restrict__ A1, const float* __restrict__ B1n,
    float* __restrict__ outAll, int chOff, int out_size) {
  int idx = blockIdx.x * 256 + threadIdx.x;   // B*128*M
  int m = idx & (Mc - 1);
  int r2 = (idx >> 10) & 127;
  int b = idx >> 17;
  float acc = b1[r2];
#pragma unroll 8
  for (int r = 0; r < 64; ++r) {
    float u = fmaf(__bfloat162float(z0[((size_t)b*64 + r)*Mc + m]), A0[r], B0n[r]);
    u = u > 0.f ? u : SLOPE * u;
    acc = fmaf(w1[r2*64 + r], u, acc);
  }
  if (WRITE) {
    float v = fmaf(acc, A1[r2], B1n[r2]);
    size_t oidx = 12288 + ((size_t)b*256 + chOff + r2)*Mc + m;
    if (oidx < (size_t)out_size) outAll[oidx] = sanf(v, 777.0f);
  } else {
    float s = acc, q = acc * acc;
#pragma unroll
    for (int d = 32; d; d >>= 1) { s += __shfl_down(s, d, 64); q += __shfl_down(q, d, 64); }
    if ((threadIdx.x & 63) == 0) { atomicAdd(&ssum[r2], s); atomicAdd(&ssq[r2], q); }
  }
}

extern "C" void kernel_launch(void* const* d_in, const int* in_sizes, int n_in,
                              void* d_out, int out_size, void* d_ws, size_t ws_size,
                              hipStream_t stream) {
  float* outb = (float*)d_out;
  int fillBlocks = (out_size + 255) / 256;
  if (n_in != 26 || in_sizes[0] != Bb*3*Npts || in_sizes[1] != Bb*29*Npts
      || in_sizes[2] != 2048) {
    fill_kernel<<<fillBlocks, 256, 0, stream>>>(outb, out_size, 7777.0f);
    return;
  }
  if (out_size != OUT_EXPECT) {
    fill_kernel<<<fillBlocks, 256, 0, stream>>>(outb, out_size, 23456.0f);
    return;
  }
  if (ws_size < WS_REQUIRED) {
    fill_kernel<<<fillBlocks, 256, 0, stream>>>(outb, out_size, 12345.0f);
    return;
  }
  const float* xyz = (const float*)d_in[0];
  const float* pf  = (const float*)d_in[1];
  char* ws = (char*)d_ws;
  int* cidx = (int*)(ws + OFF_CIDX);
  unsigned short* idx0 = (unsigned short*)(ws + OFF_IDX0);
  int* cnt0 = (int*)(ws + OFF_CNT0);
  unsigned short* idx1 = (unsigned short*)(ws + OFF_IDX1);
  int* cnt1 = (int*)(ws + OFF_CNT1);
  unsigned long long* fslots = (unsigned long long*)(ws + OFF_FSLOT);
  __hip_bfloat16* attn = (__hip_bfloat16*)(ws + OFF_ATTN);
  __hip_bfloat16* z0 = (__hip_bfloat16*)(ws + OFF_Z0);

  hipMemsetAsync(ws, 0, ZERO_BYTES, stream);                 // stats etc
  hipMemsetAsync(ws + OFF_FSLOT, 0, FSLOT_BYTES, stream);    // fps val slots
  fps_kernel<<<Bb*NBLK, 512, 0, stream>>>(xyz, pf, cidx, fslots);
  ball_kernel<<<Bb*64, 256, 0, stream>>>(xyz, pf, cidx, idx0, cnt0, idx1, cnt1);

  for (int s = 0; s < 2; ++s) {
    const float* aq = (const float*)d_in[2 + s*12 + 0];
    const float* ak = (const float*)d_in[2 + s*12 + 1];
    const float* av = (const float*)d_in[2 + s*12 + 2];
    const float* ao = (const float*)d_in[2 + s*12 + 3];
    const float* w0 = (const float*)d_in[2 + s*12 + 4];
    const float* b0 = (const float*)d_in[2 + s*12 + 5];
    const float* g0 = (const float*)d_in[2 + s*12 + 6];
    const float* t0 = (const float*)d_in[2 + s*12 + 7];
    const float* w1 = (const float*)d_in[2 + s*12 + 8];
    const float* b1 = (const float*)d_in[2 + s*12 + 9];
    const float* g1 = (const float*)d_in[2 + s*12 + 10];
    const float* t1 = (const float*)d_in[2 + s*12 + 11];
    float* st = (float*)(ws + OFF_STATS) + (size_t)s*384;
    float* nrm = (float*)(ws + OFF_NORM) + (size_t)s*384;
    float *sum0 = st, *sq0 = st + 64, *sum1 = st + 128, *sq1 = st + 256;
    float *A0 = nrm, *B0n = nrm + 64, *A1 = nrm + 128, *B1n = nrm + 256;
    if (s == 0)
      attn_kernel<32><<<Bb*Mc/4, 256, 0, stream>>>(xyz, pf, cidx, idx0, cnt0, aq, ak, av, ao, attn);
    else
      attn_kernel<64><<<Bb*Mc/4, 256, 0, stream>>>(xyz, pf, cidx, idx1, cnt1, aq, ak, av, ao, attn);
    conv0_kernel<<<Bb*64*Mc/256, 256, 0, stream>>>(attn, w0, b0, z0, sum0, sq0);
    bnfin_kernel<<<1, 64, 0, stream>>>(sum0, sq0, g0, t0, A0, B0n, 64, 1.0f/4096.0f);
    conv1_kernel<false><<<Bb*128*Mc/256, 256, 0, stream>>>(z0, A0, B0n, w1, b1, sum1, sq1,
                                                           nullptr, nullptr, nullptr, 0, out_size);
    bnfin_kernel<<<1, 128, 0, stream>>>(sum1, sq1, g1, t1, A1, B1n, 128, 1.0f/4096.0f);
    conv1_kernel<true><<<Bb*128*Mc/256, 256, 0, stream>>>(z0, A0, B0n, w1, b1, nullptr, nullptr,
                                                          A1, B1n, outb, s*128, out_size);
  }
  gather_kernel<<<48, 256, 0, stream>>>(xyz, cidx, outb, out_size);
}

// Round 11
// 2757.825 us; speedup vs baseline: 1.6131x; 1.3248x over previous
//
#include <hip/hip_runtime.h>
#include <hip/hip_bf16.h>

// PointNetMSG on MI355X. Inputs FP32, output FP32. Internal fp32, ws bf16.
// B=4, N=16384, Cs=32, M=1024, scales: (r=0.1,k=32),(r=0.2,k=64).
// R11: FPS = R8 protocol with ONE change — polling via RELAXED-AGENT loads
// (concurrent LLC reads) instead of atomicAdd(p,0) RMW spins, which serialize
// at the LLC atomic unit and queue-delay the publishes themselves
// (evidence: R8=2162us w/ sparse RMW, R10=3050us w/ dense RMW, same protocol).

static constexpr int Bb = 4;
static constexpr int Npts = 16384;
static constexpr int Mc = 1024;
static constexpr int NBLK = 16;                      // fps blocks per batch
static constexpr int OUT_EXPECT = 12288 + 1048576;   // new_xyz + feats
#define BN_EPS 1e-5f
#define SLOPE 0.02f
#define SCOPE_AGT __HIP_MEMORY_SCOPE_AGENT

// ---- workspace layout (total 1,687,552 B; ws_size >= this proven R4) ----
static constexpr size_t OFF_STATS = 33024;    // f32 [2][384]
static constexpr size_t OFF_NORM  = 36864;    // f32 [2][384]
static constexpr size_t ZERO_BYTES = 65536;
static constexpr size_t OFF_CIDX  = 65536;    // i32 [4][1024]
static constexpr size_t OFF_IDX0  = 81920;    // u16 [4][1024][32]
static constexpr size_t OFF_CNT0  = 344064;   // i32 [4][1024]
static constexpr size_t OFF_IDX1  = 360448;   // u16 [4][1024][64]
static constexpr size_t OFF_CNT1  = 884736;   // i32 [4][1024]
static constexpr size_t OFF_ATTN  = 901120;   // bf16 [4][32][1024]
static constexpr size_t OFF_Z0    = 1163264;  // bf16 [4][64][1024]
static constexpr size_t WS_REQUIRED = 1687552;
// fps val slots u64[4][1024][16] = 524288 B, aliased over attn/z0 (fps-only lifetime)
static constexpr size_t OFF_FSLOT = 901120;
static constexpr size_t FSLOT_BYTES = (size_t)Bb * Mc * NBLK * 8;

__device__ __forceinline__ float sup_at(const float* xyz, const float* pf,
                                        int b, int c, int n) {
  return (c < 3) ? xyz[((size_t)b*3 + c)*Npts + n]
                 : pf[((size_t)b*29 + (c-3))*Npts + n];
}

__device__ __forceinline__ float sanf(float v, float repl) {
  if (!(v == v) || fabsf(v) > 1e30f) v = repl;
  return v;
}

__global__ __launch_bounds__(256) void fill_kernel(float* out, int n, float val) {
  int i = blockIdx.x * 256 + threadIdx.x;
  if (i < n) out[i] = val;
}

// ---- K1: FPS v6 (= R8 v3 + load-polling). 16 blocks x 512 threads per batch.
// Distance arithmetic bit-identical to R6-R10 (sequential __fadd_rn chain).
__global__ __launch_bounds__(512, 2) void fps_kernel(
    const float* __restrict__ xyz, const float* __restrict__ pf,
    int* __restrict__ cidx, unsigned long long* __restrict__ slots) {
  const int blk = blockIdx.x;
  const int b = blk >> 4;
  const int sb = blk & (NBLK - 1);
  const int tid = threadIdx.x;
  const int lane = tid & 63, wid = tid >> 6;
  float f0[32], f1[32];
  const int p0 = sb * 1024 + tid;
  const int p1 = p0 + 512;
  float d0 = 1e10f, d1 = 1e10f;
#pragma unroll
  for (int c = 0; c < 32; ++c) {
    f0[c] = sup_at(xyz, pf, b, c, p0);
    f1[c] = sup_at(xyz, pf, b, c, p1);
  }
  __shared__ float cf[32];
  __shared__ unsigned long long red[8];
  if (sb == 0 && tid == 0) cidx[b * Mc] = 0;
  if (tid < 32) cf[tid] = sup_at(xyz, pf, b, tid, 0);   // centroid 0 = point 0
  __syncthreads();
  unsigned long long* slotb = slots + (size_t)b * Mc * NBLK;
  for (int it = 0; it < Mc - 1; ++it) {
    // ---- local distance update (exact R6 arithmetic) ----
    float cc[32];
#pragma unroll
    for (int c = 0; c < 32; ++c) cc[c] = cf[c];
    {
      float d = 0.f, e = 0.f;
#pragma unroll
      for (int c = 0; c < 32; ++c) {
        float t0 = f0[c] - cc[c];
        float s0 = __fmul_rn(t0, t0);
        d = (c == 0) ? s0 : __fadd_rn(d, s0);
        float t1 = f1[c] - cc[c];
        float s1 = __fmul_rn(t1, t1);
        e = (c == 0) ? s1 : __fadd_rn(e, s1);
      }
      d0 = fminf(d0, d);
      d1 = fminf(d1, e);
    }
    float bd; int bp;
    if (d0 >= d1) { bd = d0; bp = p0; } else { bd = d1; bp = p1; }  // p0<p1: first-index tiebreak
    unsigned long long v =
        ((unsigned long long)__float_as_uint(bd) << 32) | (unsigned int)(~(unsigned int)bp);
#pragma unroll
    for (int d = 32; d; d >>= 1) {
      unsigned long long o = __shfl_xor(v, d, 64);
      if (o > v) v = o;
    }
    if (lane == 0) red[wid] = v;
    __syncthreads();
    if (tid == 0) {
      unsigned long long vb = red[0];
#pragma unroll
      for (int w = 1; w < 8; ++w) if (red[w] > vb) vb = red[w];
      atomicMax(&slotb[(size_t)it * NBLK + sb], vb);   // single publish, val != 0 always
    }
    // ---- wave 0: poll 16 val slots via concurrent LLC reads, pick winner ----
    if (wid == 0) {
      unsigned long long myv = 0;
      if (lane < NBLK) {
        const unsigned long long* sp = &slotb[(size_t)it * NBLK + lane];
        while ((myv = __hip_atomic_load(sp, __ATOMIC_RELAXED, SCOPE_AGT)) == 0ull)
          __builtin_amdgcn_s_sleep(1);
      }
      unsigned long long mv = myv;
#pragma unroll
      for (int d = 8; d; d >>= 1) {
        unsigned long long o = __shfl_xor(mv, d, 16);
        if (o > mv) mv = o;
      }
      unsigned long long vwin = __shfl(mv, 0, 64);
      int idxWin = (int)(~(unsigned int)(vwin & 0xffffffffu)) & (Npts - 1);
      if (lane < 32) cf[lane] = sup_at(xyz, pf, b, lane, idxWin);  // read-only input: plain load
      if (lane == 0 && sb == 0) cidx[b * Mc + it + 1] = idxWin;
    }
    __syncthreads();
  }
}

// ---- K2 (runs last): new_xyz output, f32 ----
__global__ __launch_bounds__(256) void gather_kernel(
    const float* __restrict__ xyz, const int* __restrict__ cidx,
    float* __restrict__ oxyz, int out_size) {
  int idx = blockIdx.x * 256 + threadIdx.x;   // B*3*M = 12288
  if (idx >= out_size || idx >= 12288) return;
  int m = idx & (Mc - 1);
  int t = idx >> 10;          // b*3 + c
  int b = t / 3;
  int ci = cidx[b * Mc + m] & (Npts - 1);
  oxyz[idx] = sanf(xyz[(size_t)t * Npts + ci], 888.0f);
}

// ---- K3: ball grouping, both radii in one pass; u16 index lists ----
__global__ __launch_bounds__(256) void ball_kernel(
    const float* __restrict__ xyz, const float* __restrict__ pf,
    const int* __restrict__ cidx,
    unsigned short* __restrict__ idx0, int* __restrict__ cnt0,
    unsigned short* __restrict__ idx1, int* __restrict__ cnt1) {
  const int b = blockIdx.x >> 6;
  const int mt = blockIdx.x & 63;
  const int tid = threadIdx.x;
  __shared__ float cf[16][32];
  __shared__ float csq[16];
  __shared__ unsigned int ent[16][128];
  __shared__ int lcnt[16];
  for (int i = tid; i < 16 * 32; i += 256) {
    int ml = i >> 5, c = i & 31;
    int ci = cidx[b * Mc + mt * 16 + ml] & (Npts - 1);
    cf[ml][c] = sup_at(xyz, pf, b, c, ci);
  }
  if (tid < 16) lcnt[tid] = 0;
  __syncthreads();
  if (tid < 16) {
    float a = 0.f;
#pragma unroll
    for (int c = 0; c < 32; ++c) a = fmaf(cf[tid][c], cf[tid][c], a);
    csq[tid] = a;
  }
  __syncthreads();
  for (int ch = 0; ch < Npts / 256; ++ch) {
    int p = ch * 256 + tid;
    float x[32];
#pragma unroll
    for (int c = 0; c < 32; ++c) x[c] = sup_at(xyz, pf, b, c, p);
    float sp = 0.f;
#pragma unroll
    for (int c = 0; c < 32; ++c) sp = fmaf(x[c], x[c], sp);
#pragma unroll 4
    for (int ml = 0; ml < 16; ++ml) {
      float dot = 0.f;
#pragma unroll
      for (int c = 0; c < 32; ++c) dot = fmaf(cf[ml][c], x[c], dot);
      float d = sp - 2.0f * dot + csq[ml];
      if (d <= 0.04f) {
        int pos = atomicAdd(&lcnt[ml], 1);
        if (pos < 128) ent[ml][pos] = (unsigned int)p | (d <= 0.01f ? 0x80000000u : 0u);
      }
    }
  }
  __syncthreads();
  if (tid < 16) {
    int ml = tid;
    int nn = lcnt[ml]; if (nn > 128) nn = 128;
    for (int i = 1; i < nn; ++i) {   // insertion sort by point index ascending
      unsigned int e = ent[ml][i]; unsigned int key = e & 0x7fffffffu;
      int j = i - 1;
      while (j >= 0 && (ent[ml][j] & 0x7fffffffu) > key) { ent[ml][j+1] = ent[ml][j]; --j; }
      ent[ml][j+1] = e;
    }
    int gm = b * Mc + mt * 16 + ml;
    int c1 = nn < 64 ? nn : 64;
    unsigned short first1 = nn > 0 ? (unsigned short)(ent[ml][0] & 0x7fffffffu) : 0;
    unsigned short* o1 = idx1 + (size_t)gm * 64;
    for (int j = 0; j < 64; ++j)
      o1[j] = j < c1 ? (unsigned short)(ent[ml][j] & 0x7fffffffu) : first1;
    cnt1[gm] = c1;
    unsigned short* o0 = idx0 + (size_t)gm * 32;
    int c0 = 0; unsigned short first0 = 0;
    for (int i = 0; i < nn && c0 < 32; ++i) {
      if (ent[ml][i] & 0x80000000u) {
        unsigned short nv = (unsigned short)(ent[ml][i] & 0x7fffffffu);
        if (c0 == 0) first0 = nv;
        o0[c0++] = nv;
      }
    }
    for (int j = c0; j < 32; ++j) o0[j] = first0;
    cnt0[gm] = c0;
  }
}

// ---- K4: attention, one wave per centroid. o = Wv @ (sum_j softmax_j * y_j). ----
template <int K>
__global__ __launch_bounds__(256) void attn_kernel(
    const float* __restrict__ xyz, const float* __restrict__ pf,
    const int* __restrict__ cidx,
    const unsigned short* __restrict__ idxS, const int* __restrict__ cntS,
    const float* __restrict__ wq, const float* __restrict__ wk,
    const float* __restrict__ wv, const float* __restrict__ wo,
    __hip_bfloat16* __restrict__ outA) {
  __shared__ float WqL[64*33], WkL[64*33], WvL[64*33], WoL[32*65];  // +1 pad rows
  __shared__ float xv[4][32];
  __shared__ float qv[4][64];
  __shared__ float yb[4][2][32];
  __shared__ float ov[4][64];
  __shared__ int cns[4];
  const int tid = threadIdx.x;
  const int wid = tid >> 6, lane = tid & 63;
  const int gid = blockIdx.x;
  const int b = gid >> 8;
  const int m = ((gid & 255) << 2) + wid;
  for (int i = tid; i < 2048; i += 256) {
    int r = i >> 5, c = i & 31;
    WqL[r*33 + c] = wq[i];
    WkL[r*33 + c] = wk[i];
    WvL[r*33 + c] = wv[i];
    int ro = i >> 6, co = i & 63;
    WoL[ro*65 + co] = wo[i];
  }
  if (lane < 32) {
    int ci = cidx[b * Mc + m] & (Npts - 1);
    xv[wid][lane] = sup_at(xyz, pf, b, lane, ci);
  }
  if (lane == 0) cns[wid] = cntS[b * Mc + m];
  __syncthreads();
  {
    float acc = 0.f;
#pragma unroll
    for (int c = 0; c < 32; ++c) acc = fmaf(WqL[lane*33 + c], xv[wid][c], acc);
    qv[wid][lane] = acc;
  }
  __syncthreads();
  int cnt = cns[wid];
  cnt = cnt < 1 ? 1 : (cnt > K ? K : cnt);
  const int jj = lane < K ? lane : 0;
  int nj = (int)idxS[((size_t)b*Mc + m)*K + jj] & (Npts - 1);
  float y[32];
#pragma unroll
  for (int c = 0; c < 32; ++c)
    y[c] = sup_at(xyz, pf, b, c, nj) - xv[wid][c];
  float w0 = 0.f, w1 = 0.f;
#pragma unroll 2
  for (int r = 0; r < 32; ++r) {
    float k0 = 0.f, k1 = 0.f;
#pragma unroll
    for (int c = 0; c < 32; ++c) {
      k0 = fmaf(WkL[r*33 + c], y[c], k0);
      k1 = fmaf(WkL[(r+32)*33 + c], y[c], k1);
    }
    w0 = fmaf(qv[wid][r], k0, w0);
    w1 = fmaf(qv[wid][r+32], k1, w1);
  }
  const float iscale = 0.17677669529663689f;  // 1/sqrt(32)
  w0 *= iscale; w1 *= iscale;
  if (lane >= cnt) { w0 = -1e9f; w1 = -1e9f; }
  float mx0 = w0, mx1 = w1;
#pragma unroll
  for (int d = K/2; d; d >>= 1) {
    mx0 = fmaxf(mx0, __shfl_xor(mx0, d, K));
    mx1 = fmaxf(mx1, __shfl_xor(mx1, d, K));
  }
  float e0 = __expf(w0 - mx0), e1 = __expf(w1 - mx1);
  float s0 = e0, s1 = e1;
#pragma unroll
  for (int d = K/2; d; d >>= 1) {
    s0 += __shfl_xor(s0, d, K);
    s1 += __shfl_xor(s1, d, K);
  }
  float wn0 = e0 / s0, wn1 = e1 / s1;
#pragma unroll
  for (int c = 0; c < 32; ++c) {
    float t0 = wn0 * y[c], t1 = wn1 * y[c];
#pragma unroll
    for (int d = K/2; d; d >>= 1) {
      t0 += __shfl_xor(t0, d, K);
      t1 += __shfl_xor(t1, d, K);
    }
    if (lane == 0) { yb[wid][0][c] = t0; yb[wid][1][c] = t1; }
  }
  __syncthreads();
  {
    const int h = lane >> 5;
    float a2 = 0.f;
#pragma unroll
    for (int c = 0; c < 32; ++c) a2 = fmaf(WvL[lane*33 + c], yb[wid][h][c], a2);
    ov[wid][lane] = a2;
  }
  __syncthreads();
  if (lane < 32) {
    float a3 = 0.f;
#pragma unroll
    for (int r = 0; r < 64; ++r) a3 = fmaf(WoL[lane*65 + r], ov[wid][r], a3);
    outA[((size_t)b*32 + lane)*Mc + m] = __float2bfloat16(a3 + xv[wid][lane]);
  }
}

// ---- K5: conv0 (64x32) + bias, BN stats via atomics ----
__global__ __launch_bounds__(256) void conv0_kernel(
    const __hip_bfloat16* __restrict__ inA, const float* __restrict__ w0,
    const float* __restrict__ b0, __hip_bfloat16* __restrict__ z0,
    float* __restrict__ ssum, float* __restrict__ ssq) {
  int idx = blockIdx.x * 256 + threadIdx.x;   // B*64*M
  int m = idx & (Mc - 1);
  int r = (idx >> 10) & 63;
  int b = idx >> 16;
  float acc = b0[r];
#pragma unroll
  for (int c = 0; c < 32; ++c)
    acc = fmaf(w0[r*32 + c], __bfloat162float(inA[((size_t)b*32 + c)*Mc + m]), acc);
  z0[((size_t)b*64 + r)*Mc + m] = __float2bfloat16(acc);
  float s = acc, q = acc * acc;
#pragma unroll
  for (int d = 32; d; d >>= 1) { s += __shfl_down(s, d, 64); q += __shfl_down(q, d, 64); }
  if ((threadIdx.x & 63) == 0) { atomicAdd(&ssum[r], s); atomicAdd(&ssq[r], q); }
}

// ---- BN finalize ----
__global__ void bnfin_kernel(const float* __restrict__ ssum, const float* __restrict__ ssq,
    const float* __restrict__ g, const float* __restrict__ beta,
    float* __restrict__ A, float* __restrict__ Bn, int nch, float invn) {
  int r = threadIdx.x;
  if (r < nch) {
    float mu = ssum[r] * invn;
    float var = ssq[r] * invn - mu * mu;
    if (var < 0.f) var = 0.f;
    float a = g[r] * rsqrtf(var + BN_EPS);
    A[r] = a;
    Bn[r] = beta[r] - mu * a;
  }
}

// ---- K7: norm0+leaky fused conv1 (128x64). WRITE=false: stats. true: f32 out. ----
template <bool WRITE>
__global__ __launch_bounds__(256) void conv1_kernel(
    const __hip_bfloat16* __restrict__ z0, const float* __restrict__ A0, const float* __restrict__ B0n,
    const float* __restrict__ w1, const float* __restrict__ b1,
    float* __restrict__ ssum, float* __restrict__ ssq,
    const float* __restrict__ A1, const float* __restrict__ B1n,
    float* __restrict__ outAll, int chOff, int out_size) {
  int idx = blockIdx.x * 256 + threadIdx.x;   // B*128*M
  int m = idx & (Mc - 1);
  int r2 = (idx >> 10) & 127;
  int b = idx >> 17;
  float acc = b1[r2];
#pragma unroll 8
  for (int r = 0; r < 64; ++r) {
    float u = fmaf(__bfloat162float(z0[((size_t)b*64 + r)*Mc + m]), A0[r], B0n[r]);
    u = u > 0.f ? u : SLOPE * u;
    acc = fmaf(w1[r2*64 + r], u, acc);
  }
  if (WRITE) {
    float v = fmaf(acc, A1[r2], B1n[r2]);
    size_t oidx = 12288 + ((size_t)b*256 + chOff + r2)*Mc + m;
    if (oidx < (size_t)out_size) outAll[oidx] = sanf(v, 777.0f);
  } else {
    float s = acc, q = acc * acc;
#pragma unroll
    for (int d = 32; d; d >>= 1) { s += __shfl_down(s, d, 64); q += __shfl_down(q, d, 64); }
    if ((threadIdx.x & 63) == 0) { atomicAdd(&ssum[r2], s); atomicAdd(&ssq[r2], q); }
  }
}

extern "C" void kernel_launch(void* const* d_in, const int* in_sizes, int n_in,
                              void* d_out, int out_size, void* d_ws, size_t ws_size,
                              hipStream_t stream) {
  float* outb = (float*)d_out;
  int fillBlocks = (out_size + 255) / 256;
  if (n_in != 26 || in_sizes[0] != Bb*3*Npts || in_sizes[1] != Bb*29*Npts
      || in_sizes[2] != 2048) {
    fill_kernel<<<fillBlocks, 256, 0, stream>>>(outb, out_size, 7777.0f);
    return;
  }
  if (out_size != OUT_EXPECT) {
    fill_kernel<<<fillBlocks, 256, 0, stream>>>(outb, out_size, 23456.0f);
    return;
  }
  if (ws_size < WS_REQUIRED) {
    fill_kernel<<<fillBlocks, 256, 0, stream>>>(outb, out_size, 12345.0f);
    return;
  }
  const float* xyz = (const float*)d_in[0];
  const float* pf  = (const float*)d_in[1];
  char* ws = (char*)d_ws;
  int* cidx = (int*)(ws + OFF_CIDX);
  unsigned short* idx0 = (unsigned short*)(ws + OFF_IDX0);
  int* cnt0 = (int*)(ws + OFF_CNT0);
  unsigned short* idx1 = (unsigned short*)(ws + OFF_IDX1);
  int* cnt1 = (int*)(ws + OFF_CNT1);
  unsigned long long* fslots = (unsigned long long*)(ws + OFF_FSLOT);
  __hip_bfloat16* attn = (__hip_bfloat16*)(ws + OFF_ATTN);
  __hip_bfloat16* z0 = (__hip_bfloat16*)(ws + OFF_Z0);

  hipMemsetAsync(ws, 0, ZERO_BYTES, stream);                 // stats etc
  hipMemsetAsync(ws + OFF_FSLOT, 0, FSLOT_BYTES, stream);    // fps val slots
  fps_kernel<<<Bb*NBLK, 512, 0, stream>>>(xyz, pf, cidx, fslots);
  ball_kernel<<<Bb*64, 256, 0, stream>>>(xyz, pf, cidx, idx0, cnt0, idx1, cnt1);

  for (int s = 0; s < 2; ++s) {
    const float* aq = (const float*)d_in[2 + s*12 + 0];
    const float* ak = (const float*)d_in[2 + s*12 + 1];
    const float* av = (const float*)d_in[2 + s*12 + 2];
    const float* ao = (const float*)d_in[2 + s*12 + 3];
    const float* w0 = (const float*)d_in[2 + s*12 + 4];
    const float* b0 = (const float*)d_in[2 + s*12 + 5];
    const float* g0 = (const float*)d_in[2 + s*12 + 6];
    const float* t0 = (const float*)d_in[2 + s*12 + 7];
    const float* w1 = (const float*)d_in[2 + s*12 + 8];
    const float* b1 = (const float*)d_in[2 + s*12 + 9];
    const float* g1 = (const float*)d_in[2 + s*12 + 10];
    const float* t1 = (const float*)d_in[2 + s*12 + 11];
    float* st = (float*)(ws + OFF_STATS) + (size_t)s*384;
    float* nrm = (float*)(ws + OFF_NORM) + (size_t)s*384;
    float *sum0 = st, *sq0 = st + 64, *sum1 = st + 128, *sq1 = st + 256;
    float *A0 = nrm, *B0n = nrm + 64, *A1 = nrm + 128, *B1n = nrm + 256;
    if (s == 0)
      attn_kernel<32><<<Bb*Mc/4, 256, 0, stream>>>(xyz, pf, cidx, idx0, cnt0, aq, ak, av, ao, attn);
    else
      attn_kernel<64><<<Bb*Mc/4, 256, 0, stream>>>(xyz, pf, cidx, idx1, cnt1, aq, ak, av, ao, attn);
    conv0_kernel<<<Bb*64*Mc/256, 256, 0, stream>>>(attn, w0, b0, z0, sum0, sq0);
    bnfin_kernel<<<1, 64, 0, stream>>>(sum0, sq0, g0, t0, A0, B0n, 64, 1.0f/4096.0f);
    conv1_kernel<false><<<Bb*128*Mc/256, 256, 0, stream>>>(z0, A0, B0n, w1, b1, sum1, sq1,
                                                           nullptr, nullptr, nullptr, 0, out_size);
    bnfin_kernel<<<1, 128, 0, stream>>>(sum1, sq1, g1, t1, A1, B1n, 128, 1.0f/4096.0f);
    conv1_kernel<true><<<Bb*128*Mc/256, 256, 0, stream>>>(z0, A0, B0n, w1, b1, nullptr, nullptr,
                                                          A1, B1n, outb, s*128, out_size);
  }
  gather_kernel<<<48, 256, 0, stream>>>(xyz, cidx, outb, out_size);
}